// Round 8
// baseline (368.367 us; speedup 1.0000x reference)
//
#include <hip/hip_runtime.h>

#define NBINS 1000

// -------- Kernel 1: LDS-privatized histogram --------
// Memory-bound: one float4-coalesced pass over 268 MB (roofline ~43 µs at
// 6.3 TB/s). LDS atomics (random bins, ~4-way bank aliasing) hide under the
// HBM drain.
__global__ __launch_bounds__(256) void hist_kernel(
    const float* __restrict__ x, long long n,
    unsigned int* __restrict__ gcounts)
{
    __shared__ unsigned int lh[NBINS];
    for (int i = threadIdx.x; i < NBINS; i += 256) lh[i] = 0u;
    __syncthreads();

    const long long n4 = n >> 2;                       // float4 chunks
    const float4* __restrict__ x4 = (const float4*)x;
    const long long stride = (long long)gridDim.x * 256;

    for (long long i = (long long)blockIdx.x * 256 + threadIdx.x; i < n4; i += stride) {
        float4 v = x4[i];
        // values are exact small integers in [0, NBINS); truncating cast
        // matches x.astype(int32)
        atomicAdd(&lh[(unsigned)(int)v.x], 1u);
        atomicAdd(&lh[(unsigned)(int)v.y], 1u);
        atomicAdd(&lh[(unsigned)(int)v.z], 1u);
        atomicAdd(&lh[(unsigned)(int)v.w], 1u);
    }

    // scalar tail (n % 4) — covered by the first (n - n4*4) global threads
    const long long tail_start = n4 << 2;
    const long long gtid = (long long)blockIdx.x * 256 + threadIdx.x;
    if (gtid < (n - tail_start)) {
        atomicAdd(&lh[(unsigned)(int)x[tail_start + gtid]], 1u);
    }

    __syncthreads();
    for (int i = threadIdx.x; i < NBINS; i += 256) {
        unsigned int c = lh[i];
        if (c) atomicAdd(&gcounts[i], c);
    }
}

// -------- Kernel 2: unique(size=NBINS, fill_value=0) compaction --------
// One block, 1024 threads. Inclusive Hillis-Steele scan over occupancy flags,
// then scatter {value, count} to compacted sorted positions; fill rest with 0.
// Output dtype: harness reads d_out as RAW int32 for an int32-returning
// reference (per its out_dtype_str=='int32' readback path) — write int32.
__global__ __launch_bounds__(1024) void finalize_kernel(
    const unsigned int* __restrict__ gcounts, int* __restrict__ out)
{
    __shared__ unsigned int sc[1024];
    const int t = threadIdx.x;

    const unsigned int c    = (t < NBINS) ? gcounts[t] : 0u;
    const unsigned int flag = (t < NBINS && c > 0u) ? 1u : 0u;
    sc[t] = flag;
    __syncthreads();

    for (int off = 1; off < 1024; off <<= 1) {
        unsigned int add = (t >= off) ? sc[t - off] : 0u;
        __syncthreads();
        sc[t] += add;
        __syncthreads();
    }

    // zero-fill both halves (fill_value=0 / count 0); d_out is poisoned 0xAA
    // before every timed launch, so every element must be written.
    if (t < NBINS) { out[t] = 0; out[NBINS + t] = 0; }
    __syncthreads();

    if (flag) {
        const unsigned int pos = sc[t] - 1u;   // exclusive-scan position
        out[pos]         = t;                  // sorted unique value
        out[NBINS + pos] = (int)c;             // its count
    }
}

extern "C" void kernel_launch(void* const* d_in, const int* in_sizes, int n_in,
                              void* d_out, int out_size, void* d_ws, size_t ws_size,
                              hipStream_t stream) {
    const float* x = (const float*)d_in[0];
    const long long n = (long long)in_sizes[0];

    unsigned int* gcounts = (unsigned int*)d_ws;
    hipMemsetAsync(gcounts, 0, NBINS * sizeof(unsigned int), stream);

    const int blocks = 2048;   // ~8 blocks/CU, grid-stride (G11 memory-bound sizing)
    hist_kernel<<<blocks, 256, 0, stream>>>(x, n, gcounts);
    finalize_kernel<<<1, 1024, 0, stream>>>(gcounts, (int*)d_out);
}